// Round 3
// baseline (6204.272 us; speedup 1.0000x reference)
//
#include <hip/hip_runtime.h>

// ---------------------------------------------------------------------------
// ViT forward on MI355X. bf16 MFMA GEMMs (m97 structure: 128x128 tile, 4 waves,
// 16x16x32 MFMA, global_load_lds 16B staging), fp32 residual stream.
// Workspace peak ~191 MB (S per batch-head; x1/obuf and qkv/hbuf aliased).
// ---------------------------------------------------------------------------

typedef unsigned short u16;
typedef __bf16 bf16v8 __attribute__((ext_vector_type(8)));
typedef float f32v4 __attribute__((ext_vector_type(4)));

#define NTOK   4608
#define TTOT   9216
#define DIMD   1024
#define H3     3072
#define MLPH   4096
#define NHEAD  4
#define DHEAD  256
#define NLAYER 4

__device__ __forceinline__ u16 f2bf(float f) {
  unsigned u = __float_as_uint(f);
  u += 0x7fffu + ((u >> 16) & 1u);   // RNE
  return (u16)(u >> 16);
}
__device__ __forceinline__ float bf2f(u16 b) {
  return __uint_as_float(((unsigned)b) << 16);
}
__device__ __forceinline__ void gload16(const void* g, void* l) {
  __builtin_amdgcn_global_load_lds((__attribute__((address_space(1))) void*)g,
                                   (__attribute__((address_space(3))) void*)l,
                                   16, 0, 0);
}

// ---------------- weight transpose fp32(R,C) -> bf16(C,R) ----------------
__global__ __launch_bounds__(256) void transpose_w(
    const float* __restrict__ src, u16* __restrict__ dst, int R, int C) {
  __shared__ float tile[32][33];
  const int c0 = blockIdx.x * 32, r0 = blockIdx.y * 32;
  const int tx = threadIdx.x, ty = threadIdx.y;
#pragma unroll
  for (int i = 0; i < 32; i += 8)
    tile[ty + i][tx] = src[(size_t)(r0 + ty + i) * C + c0 + tx];
  __syncthreads();
#pragma unroll
  for (int i = 0; i < 32; i += 8)
    dst[(size_t)(c0 + ty + i) * R + r0 + tx] = f2bf(tile[tx][ty + i]);
}

__global__ __launch_bounds__(256) void convert_bf16(
    const float* __restrict__ src, u16* __restrict__ dst, int n) {
  int i = blockIdx.x * 256 + threadIdx.x;
  if (i < n) dst[i] = f2bf(src[i]);
}

// ---------------- patch extraction: img -> A[9216][256] bf16 ----------------
__global__ __launch_bounds__(256) void patch_extract(
    const float* __restrict__ img, u16* __restrict__ A) {
  const int t = blockIdx.x;       // token 0..9215
  const int k = threadIdx.x;      // 0..255
  const int b = t / NTOK, r = t % NTOK;
  const int d = r / 576, r2 = r % 576;
  const int hh = r2 / 24, ww = r2 % 24;
  const int ci = k >> 7, k2 = k & 127;
  const int kd = k2 >> 6, k3 = k2 & 63;
  const int kh = k3 >> 3, kw = k3 & 7;
  const size_t idx =
      ((size_t)((b * 2 + ci) * 16 + (2 * d + kd))) * (192 * 192) +
      (size_t)(8 * hh + kh) * 192 + (8 * ww + kw);
  A[(size_t)t * 256 + k] = f2bf(img[idx]);
}

// ---------------- LayerNorm (row=1024). OUTF32: 1 -> fp32, 0 -> bf16 --------
template <int OUTF32>
__global__ __launch_bounds__(256) void ln_kernel(
    const float* __restrict__ x, const float* __restrict__ g,
    const float* __restrict__ bta, void* __restrict__ out) {
  const size_t row = blockIdx.x;
  const int t = threadIdx.x;
  const float4 v = ((const float4*)(x + row * DIMD))[t];
  float s = v.x + v.y + v.z + v.w;
  float ss = v.x * v.x + v.y * v.y + v.z * v.z + v.w * v.w;
#pragma unroll
  for (int o = 32; o; o >>= 1) {
    s += __shfl_xor(s, o, 64);
    ss += __shfl_xor(ss, o, 64);
  }
  __shared__ float sh[8];
  if ((t & 63) == 0) { sh[t >> 6] = s; sh[4 + (t >> 6)] = ss; }
  __syncthreads();
  s = sh[0] + sh[1] + sh[2] + sh[3];
  ss = sh[4] + sh[5] + sh[6] + sh[7];
  const float mu = s * (1.f / DIMD);
  const float rs = rsqrtf(ss * (1.f / DIMD) - mu * mu + 1e-5f);
  const float4 gg = ((const float4*)g)[t];
  const float4 bb = ((const float4*)bta)[t];
  const float y0 = (v.x - mu) * rs * gg.x + bb.x;
  const float y1 = (v.y - mu) * rs * gg.y + bb.y;
  const float y2 = (v.z - mu) * rs * gg.z + bb.z;
  const float y3 = (v.w - mu) * rs * gg.w + bb.w;
  if (OUTF32) {
    float4 o4; o4.x = y0; o4.y = y1; o4.z = y2; o4.w = y3;
    ((float4*)out)[row * 256 + t] = o4;
  } else {
    ushort4 o4;
    o4.x = f2bf(y0); o4.y = f2bf(y1); o4.z = f2bf(y2); o4.w = f2bf(y3);
    ((ushort4*)out)[row * 256 + t] = o4;
  }
}

// ---------------- transpose V slice of qkv -> vT[b][h][256][4608] -----------
__global__ __launch_bounds__(256) void transpose_v(
    const u16* __restrict__ qkv, u16* __restrict__ vT) {
  const int bh = blockIdx.z, b = bh >> 2, h = bh & 3;
  const u16* src = qkv + (size_t)b * NTOK * H3 + 2048 + h * DHEAD;
  u16* dst = vT + (size_t)bh * DHEAD * NTOK;
  __shared__ u16 tile[32][33];
  const int t0 = blockIdx.x * 32, d0 = blockIdx.y * 32;
  const int tx = threadIdx.x, ty = threadIdx.y;
#pragma unroll
  for (int i = 0; i < 32; i += 8)
    tile[ty + i][tx] = src[(size_t)(t0 + ty + i) * H3 + d0 + tx];
  __syncthreads();
#pragma unroll
  for (int i = 0; i < 32; i += 8)
    dst[(size_t)(d0 + ty + i) * NTOK + t0 + tx] = tile[tx][ty + i];
}

// ---------------- row softmax in-place on bf16 S[4608][4608] ----------------
__global__ __launch_bounds__(256) void softmax_rows(u16* __restrict__ S) {
  const size_t base = (size_t)blockIdx.x * NTOK;
  u16* row = S + base;
  const int t = threadIdx.x;
  float v[18];
  float mx = -1e30f;
#pragma unroll
  for (int j = 0; j < 9; j++) {
    ushort2 p = ((const ushort2*)row)[t + j * 256];
    v[2 * j] = bf2f(p.x);
    v[2 * j + 1] = bf2f(p.y);
    mx = fmaxf(mx, fmaxf(v[2 * j], v[2 * j + 1]));
  }
#pragma unroll
  for (int o = 32; o; o >>= 1) mx = fmaxf(mx, __shfl_xor(mx, o, 64));
  __shared__ float sh[4];
  const int wv = t >> 6;
  if ((t & 63) == 0) sh[wv] = mx;
  __syncthreads();
  mx = fmaxf(fmaxf(sh[0], sh[1]), fmaxf(sh[2], sh[3]));
  __syncthreads();
  float sum = 0.f;
#pragma unroll
  for (int j = 0; j < 18; j++) { v[j] = __expf(v[j] - mx); sum += v[j]; }
#pragma unroll
  for (int o = 32; o; o >>= 1) sum += __shfl_xor(sum, o, 64);
  if ((t & 63) == 0) sh[wv] = sum;
  __syncthreads();
  sum = sh[0] + sh[1] + sh[2] + sh[3];
  const float inv = 1.f / sum;
#pragma unroll
  for (int j = 0; j < 9; j++) {
    ushort2 p;
    p.x = f2bf(v[2 * j] * inv);
    p.y = f2bf(v[2 * j + 1] * inv);
    ((ushort2*)row)[t + j * 256] = p;
  }
}

// ---------------- GEMM: C[M,N] = A[M,K] * Bt[N,K]^T  (all bf16, fp32 acc) ---
// 128x128 tile, 4 waves (2x2), 16x16x32 MFMA, global_load_lds staging.
// EPI: 0 store bf16; 1 store bf16*scale; 2 fp32 resid += acc+bias;
//      3 bf16 gelu(acc+bias); 4 fp32 acc+bias+pos (conv epilogue).
template <int EPI>
__global__ __launch_bounds__(256) void gemm_bt(
    const u16* __restrict__ A, int lda,
    const u16* __restrict__ Bt, int ldb,
    int K, void* __restrict__ Cp, int ldc,
    const float* __restrict__ bias, const float* __restrict__ extra,
    float scale) {
  __shared__ __align__(16) u16 As[128 * 32];
  __shared__ __align__(16) u16 Bs[128 * 32];
  const int tid = threadIdx.x;
  const int bm = blockIdx.x, bn = blockIdx.y;

  const int c0 = tid, c1 = tid + 256;
  const u16* Ab = A + (size_t)(bm * 128) * lda;
  const u16* Bb = Bt + (size_t)(bn * 128) * ldb;
  const size_t a0 = (size_t)(c0 >> 2) * lda + (c0 & 3) * 8;
  const size_t a1 = (size_t)(c1 >> 2) * lda + (c1 & 3) * 8;
  const size_t b0 = (size_t)(c0 >> 2) * ldb + (c0 & 3) * 8;
  const size_t b1 = (size_t)(c1 >> 2) * ldb + (c1 & 3) * 8;

  const int lane = tid & 63;
  const int wv = tid >> 6;
  const int wm = (wv >> 1) * 64;
  const int wn = (wv & 1) * 64;
  const int fr = lane & 15;
  const int fk = (lane >> 4) * 8;

  f32v4 acc[4][4];
#pragma unroll
  for (int m = 0; m < 4; m++)
#pragma unroll
    for (int n = 0; n < 4; n++) acc[m][n] = (f32v4){0.f, 0.f, 0.f, 0.f};

  for (int k0 = 0; k0 < K; k0 += 32) {
    __syncthreads();   // previous compute done before overwriting LDS
    gload16(Ab + a0 + k0, As + (size_t)c0 * 8);
    gload16(Ab + a1 + k0, As + (size_t)c1 * 8);
    gload16(Bb + b0 + k0, Bs + (size_t)c0 * 8);
    gload16(Bb + b1 + k0, Bs + (size_t)c1 * 8);
    __syncthreads();   // compiler emits vmcnt(0) drain before barrier

    bf16v8 af[4], bq[4];
#pragma unroll
    for (int m = 0; m < 4; m++)
      af[m] = *reinterpret_cast<const bf16v8*>(&As[(wm + m * 16 + fr) * 32 + fk]);
#pragma unroll
    for (int n = 0; n < 4; n++)
      bq[n] = *reinterpret_cast<const bf16v8*>(&Bs[(wn + n * 16 + fr) * 32 + fk]);
#pragma unroll
    for (int m = 0; m < 4; m++)
#pragma unroll
      for (int n = 0; n < 4; n++)
        acc[m][n] =
            __builtin_amdgcn_mfma_f32_16x16x32_bf16(af[m], bq[n], acc[m][n], 0, 0, 0);
  }

  // epilogue: C/D frag layout col=lane&15, row=(lane>>4)*4+j  [m89-verified]
  const int rbase = bm * 128 + wm + (lane >> 4) * 4;
  const int cbase = bn * 128 + wn + fr;
#pragma unroll
  for (int m = 0; m < 4; m++) {
#pragma unroll
    for (int n = 0; n < 4; n++) {
      const int col = cbase + n * 16;
#pragma unroll
      for (int j = 0; j < 4; j++) {
        const int rowi = rbase + m * 16 + j;
        const float v = acc[m][n][j];
        if (EPI == 0) {
          ((u16*)Cp)[(size_t)rowi * ldc + col] = f2bf(v);
        } else if (EPI == 1) {
          ((u16*)Cp)[(size_t)rowi * ldc + col] = f2bf(v * scale);
        } else if (EPI == 2) {
          float* p = (float*)Cp + (size_t)rowi * ldc + col;
          *p += v + bias[col];
        } else if (EPI == 3) {
          float t = v + bias[col];
          t = 0.5f * t * (1.f + erff(t * 0.70710678118654752f));
          ((u16*)Cp)[(size_t)rowi * ldc + col] = f2bf(t);
        } else {
          ((float*)Cp)[(size_t)rowi * ldc + col] =
              v + bias[col] + extra[(size_t)(rowi % NTOK) * DIMD + col];
        }
      }
    }
  }
}

// ---------------------------------------------------------------------------
// workspace layout (bytes) — peak ~191 MB
// ---------------------------------------------------------------------------
#define SZ_QKVT ((size_t)H3 * DIMD * 2)
#define SZ_OUTT ((size_t)DIMD * DIMD * 2)
#define SZ_FC1T ((size_t)MLPH * DIMD * 2)
#define SZ_FC2T ((size_t)DIMD * MLPH * 2)
#define SZ_CONVW ((size_t)DIMD * 256 * 2)
#define SZ_X ((size_t)TTOT * DIMD * 4)
#define SZ_XO ((size_t)TTOT * DIMD * 2)            // x1 | obuf (disjoint lifetimes)
#define SZ_BIGA ((size_t)TTOT * H3 * 2 + (size_t)8 * DHEAD * NTOK * 2) // qkv+vT | hbuf
#define SZ_S ((size_t)NTOK * NTOK * 2)             // one (batch,head): 42.5 MB | patchA

#define OFF_QKVT ((size_t)0)
#define OFF_OUTT (OFF_QKVT + SZ_QKVT)
#define OFF_FC1T (OFF_OUTT + SZ_OUTT)
#define OFF_FC2T (OFF_FC1T + SZ_FC1T)
#define OFF_CONVW (OFF_FC2T + SZ_FC2T)
#define OFF_X (OFF_CONVW + SZ_CONVW)
#define OFF_XO (OFF_X + SZ_X)
#define OFF_BIGA (OFF_XO + SZ_XO)
#define OFF_S (OFF_BIGA + SZ_BIGA)
#define WS_NEED (OFF_S + SZ_S)     // ~200.3e6 bytes

extern "C" void kernel_launch(void* const* d_in, const int* in_sizes, int n_in,
                              void* d_out, int out_size, void* d_ws, size_t ws_size,
                              hipStream_t stream) {
  const float* img = (const float*)d_in[0];
  const float* conv_w = (const float*)d_in[1];
  const float* conv_b = (const float*)d_in[2];
  const float* pos = (const float*)d_in[3];
  const float* ln1_g = (const float*)d_in[4];
  const float* ln1_b = (const float*)d_in[5];
  const float* qkv_w = (const float*)d_in[6];
  const float* out_w = (const float*)d_in[7];
  const float* out_b = (const float*)d_in[8];
  const float* ln2_g = (const float*)d_in[9];
  const float* ln2_b = (const float*)d_in[10];
  const float* fc1_w = (const float*)d_in[11];
  const float* fc1_b = (const float*)d_in[12];
  const float* fc2_w = (const float*)d_in[13];
  const float* fc2_b = (const float*)d_in[14];
  const float* lnf_g = (const float*)d_in[15];
  const float* lnf_b = (const float*)d_in[16];
  float* out = (float*)d_out;

  // Diagnostic guard: if scratch is too small, bail (harness then reports
  // pure-poison absmax ~488 instead of a GPU memory fault).
  if (ws_size < WS_NEED) return;

  char* ws = (char*)d_ws;
  u16* qkvT = (u16*)(ws + OFF_QKVT);
  u16* outT = (u16*)(ws + OFF_OUTT);
  u16* fc1T = (u16*)(ws + OFF_FC1T);
  u16* fc2T = (u16*)(ws + OFF_FC2T);
  u16* convW = (u16*)(ws + OFF_CONVW);
  float* x = (float*)(ws + OFF_X);
  u16* x1 = (u16*)(ws + OFF_XO);
  u16* obuf = (u16*)(ws + OFF_XO);     // aliased with x1 (disjoint lifetime)
  u16* qkv = (u16*)(ws + OFF_BIGA);
  u16* vT = (u16*)(ws + OFF_BIGA + (size_t)TTOT * H3 * 2);
  u16* hbuf = (u16*)(ws + OFF_BIGA);   // aliased over qkv+vT (MLP phase)
  u16* S = (u16*)(ws + OFF_S);
  u16* patchA = (u16*)(ws + OFF_S);    // aliased (pre-layer phase only)

  const dim3 tb(32, 8);

  // ---- patch embed ----
  convert_bf16<<<1024, 256, 0, stream>>>(conv_w, convW, DIMD * 256);
  patch_extract<<<TTOT, 256, 0, stream>>>(img, patchA);
  gemm_bt<4><<<dim3(TTOT / 128, DIMD / 128, 1), 256, 0, stream>>>(
      patchA, 256, convW, 256, 256, x, DIMD, conv_b, pos, 1.f);

  for (int l = 0; l < NLAYER; l++) {
    // per-layer weight prep (bf16, N-major)
    transpose_w<<<dim3(H3 / 32, DIMD / 32, 1), tb, 0, stream>>>(
        qkv_w + (size_t)l * DIMD * H3, qkvT, DIMD, H3);
    transpose_w<<<dim3(DIMD / 32, DIMD / 32, 1), tb, 0, stream>>>(
        out_w + (size_t)l * DIMD * DIMD, outT, DIMD, DIMD);
    transpose_w<<<dim3(MLPH / 32, DIMD / 32, 1), tb, 0, stream>>>(
        fc1_w + (size_t)l * DIMD * MLPH, fc1T, DIMD, MLPH);
    transpose_w<<<dim3(DIMD / 32, MLPH / 32, 1), tb, 0, stream>>>(
        fc2_w + (size_t)l * MLPH * DIMD, fc2T, MLPH, DIMD);

    // LN1 -> x1 (bf16)
    ln_kernel<0><<<TTOT, 256, 0, stream>>>(x, ln1_g + l * DIMD, ln1_b + l * DIMD, x1);
    // QKV
    gemm_bt<0><<<dim3(TTOT / 128, H3 / 128, 1), 256, 0, stream>>>(
        x1, DIMD, qkvT, DIMD, DIMD, qkv, H3, nullptr, nullptr, 1.f);
    // V -> vT
    transpose_v<<<dim3(NTOK / 32, DHEAD / 32, 8), tb, 0, stream>>>(qkv, vT);

    for (int b = 0; b < 2; b++) {
      const u16* qb = qkv + (size_t)b * NTOK * H3;
      for (int h = 0; h < NHEAD; h++) {
        // S = Q K^T * scale
        gemm_bt<1><<<dim3(NTOK / 128, NTOK / 128, 1), 256, 0, stream>>>(
            qb + h * DHEAD, H3, qb + DIMD + h * DHEAD, H3, DHEAD,
            S, NTOK, nullptr, nullptr, 0.03125f);
        softmax_rows<<<dim3(NTOK, 1, 1), 256, 0, stream>>>(S);
        // o = P V  (into obuf columns h*256..h*256+255)
        gemm_bt<0><<<dim3(NTOK / 128, DHEAD / 128, 1), 256, 0, stream>>>(
            S, NTOK, vT + (size_t)(b * NHEAD + h) * DHEAD * NTOK, NTOK, NTOK,
            obuf + (size_t)b * NTOK * DIMD + h * DHEAD, DIMD,
            nullptr, nullptr, 1.f);
      }
    }
    // x += o @ out_w + out_b
    gemm_bt<2><<<dim3(TTOT / 128, DIMD / 128, 1), 256, 0, stream>>>(
        obuf, DIMD, outT, DIMD, DIMD, x, DIMD, out_b + l * DIMD, nullptr, 1.f);
    // LN2 -> x1
    ln_kernel<0><<<TTOT, 256, 0, stream>>>(x, ln2_g + l * DIMD, ln2_b + l * DIMD, x1);
    // h = gelu(x1 @ fc1 + b)
    gemm_bt<3><<<dim3(TTOT / 128, MLPH / 128, 1), 256, 0, stream>>>(
        x1, DIMD, fc1T, DIMD, DIMD, hbuf, MLPH, fc1_b + l * MLPH, nullptr, 1.f);
    // x += h @ fc2 + b
    gemm_bt<2><<<dim3(TTOT / 128, DIMD / 128, 1), 256, 0, stream>>>(
        hbuf, MLPH, fc2T, MLPH, MLPH, x, DIMD, fc2_b + l * DIMD, nullptr, 1.f);
  }

  // final LN -> fp32 out
  ln_kernel<1><<<TTOT, 256, 0, stream>>>(x, lnf_g, lnf_b, out);
}

// Round 5
// 3800.140 us; speedup vs baseline: 1.6326x; 1.6326x over previous
//
#include <hip/hip_runtime.h>

// ---------------------------------------------------------------------------
// ViT forward on MI355X. bf16 MFMA GEMMs (m97 structure) + fused flash attn.
// fp32 residual stream. Workspace peak ~158 MB.
// ---------------------------------------------------------------------------

typedef unsigned short u16;
typedef __bf16 bf16v8 __attribute__((ext_vector_type(8)));
typedef float f32v4 __attribute__((ext_vector_type(4)));

#define NTOK   4608
#define TTOT   9216
#define DIMD   1024
#define H3     3072
#define MLPH   4096
#define NHEAD  4
#define DHEAD  256
#define NLAYER 4
#define QBLK   128
#define KBLK   64
#define NKT    (NTOK / KBLK)   // 72

__device__ __forceinline__ u16 f2bf(float f) {
  unsigned u = __float_as_uint(f);
  u += 0x7fffu + ((u >> 16) & 1u);   // RNE
  return (u16)(u >> 16);
}
__device__ __forceinline__ float bf2f(u16 b) {
  return __uint_as_float(((unsigned)b) << 16);
}
__device__ __forceinline__ void gload16(const void* g, void* l) {
  __builtin_amdgcn_global_load_lds((__attribute__((address_space(1))) void*)g,
                                   (__attribute__((address_space(3))) void*)l,
                                   16, 0, 0);
}

// ---------------- weight transpose fp32(R,C) -> bf16(C,R) ----------------
__global__ __launch_bounds__(256) void transpose_w(
    const float* __restrict__ src, u16* __restrict__ dst, int R, int C) {
  __shared__ float tile[32][33];
  const int c0 = blockIdx.x * 32, r0 = blockIdx.y * 32;
  const int tx = threadIdx.x, ty = threadIdx.y;
#pragma unroll
  for (int i = 0; i < 32; i += 8)
    tile[ty + i][tx] = src[(size_t)(r0 + ty + i) * C + c0 + tx];
  __syncthreads();
#pragma unroll
  for (int i = 0; i < 32; i += 8)
    dst[(size_t)(c0 + ty + i) * R + r0 + tx] = f2bf(tile[tx][ty + i]);
}

__global__ __launch_bounds__(256) void convert_bf16(
    const float* __restrict__ src, u16* __restrict__ dst, int n) {
  int i = blockIdx.x * 256 + threadIdx.x;
  if (i < n) dst[i] = f2bf(src[i]);
}

// ---------------- patch extraction: img -> A[9216][256] bf16 ----------------
__global__ __launch_bounds__(256) void patch_extract(
    const float* __restrict__ img, u16* __restrict__ A) {
  const int t = blockIdx.x;
  const int k = threadIdx.x;
  const int b = t / NTOK, r = t % NTOK;
  const int d = r / 576, r2 = r % 576;
  const int hh = r2 / 24, ww = r2 % 24;
  const int ci = k >> 7, k2 = k & 127;
  const int kd = k2 >> 6, k3 = k2 & 63;
  const int kh = k3 >> 3, kw = k3 & 7;
  const size_t idx =
      ((size_t)((b * 2 + ci) * 16 + (2 * d + kd))) * (192 * 192) +
      (size_t)(8 * hh + kh) * 192 + (8 * ww + kw);
  A[(size_t)t * 256 + k] = f2bf(img[idx]);
}

// ---------------- LayerNorm (row=1024). OUTF32: 1 -> fp32, 0 -> bf16 --------
template <int OUTF32>
__global__ __launch_bounds__(256) void ln_kernel(
    const float* __restrict__ x, const float* __restrict__ g,
    const float* __restrict__ bta, void* __restrict__ out) {
  const size_t row = blockIdx.x;
  const int t = threadIdx.x;
  const float4 v = ((const float4*)(x + row * DIMD))[t];
  float s = v.x + v.y + v.z + v.w;
  float ss = v.x * v.x + v.y * v.y + v.z * v.z + v.w * v.w;
#pragma unroll
  for (int o = 32; o; o >>= 1) {
    s += __shfl_xor(s, o, 64);
    ss += __shfl_xor(ss, o, 64);
  }
  __shared__ float sh[8];
  if ((t & 63) == 0) { sh[t >> 6] = s; sh[4 + (t >> 6)] = ss; }
  __syncthreads();
  s = sh[0] + sh[1] + sh[2] + sh[3];
  ss = sh[4] + sh[5] + sh[6] + sh[7];
  const float mu = s * (1.f / DIMD);
  const float rs = rsqrtf(ss * (1.f / DIMD) - mu * mu + 1e-5f);
  const float4 gg = ((const float4*)g)[t];
  const float4 bb = ((const float4*)bta)[t];
  const float y0 = (v.x - mu) * rs * gg.x + bb.x;
  const float y1 = (v.y - mu) * rs * gg.y + bb.y;
  const float y2 = (v.z - mu) * rs * gg.z + bb.z;
  const float y3 = (v.w - mu) * rs * gg.w + bb.w;
  if (OUTF32) {
    float4 o4; o4.x = y0; o4.y = y1; o4.z = y2; o4.w = y3;
    ((float4*)out)[row * 256 + t] = o4;
  } else {
    ushort4 o4;
    o4.x = f2bf(y0); o4.y = f2bf(y1); o4.z = f2bf(y2); o4.w = f2bf(y3);
    ((ushort4*)out)[row * 256 + t] = o4;
  }
}

// ---------------- transpose V slice of qkv -> vT[b][h][256][4608] -----------
__global__ __launch_bounds__(256) void transpose_v(
    const u16* __restrict__ qkv, u16* __restrict__ vT) {
  const int bh = blockIdx.z, b = bh >> 2, h = bh & 3;
  const u16* src = qkv + (size_t)b * NTOK * H3 + 2048 + h * DHEAD;
  u16* dst = vT + (size_t)bh * DHEAD * NTOK;
  __shared__ u16 tile[32][33];
  const int t0 = blockIdx.x * 32, d0 = blockIdx.y * 32;
  const int tx = threadIdx.x, ty = threadIdx.y;
#pragma unroll
  for (int i = 0; i < 32; i += 8)
    tile[ty + i][tx] = src[(size_t)(t0 + ty + i) * H3 + d0 + tx];
  __syncthreads();
#pragma unroll
  for (int i = 0; i < 32; i += 8)
    dst[(size_t)(d0 + ty + i) * NTOK + t0 + tx] = tile[tx][ty + i];
}

// ---------------------------------------------------------------------------
// Fused flash attention. Grid: (NTOK/QBLK, 8 bh). 512 threads = 8 waves.
// Wave owns 16 Q-rows. K/V tiles (64 tok) double-buffered in LDS, XOR-swizzle
// ((row&7)<<4) with pre-swizzled global source (rule 21). Q in registers.
// Online softmax in C-frag layout; P via per-wave LDS scratch -> A-frags.
// ---------------------------------------------------------------------------
__global__ __launch_bounds__(512) void flash_attn(
    const u16* __restrict__ qkv, const u16* __restrict__ vT,
    u16* __restrict__ obuf) {
  __shared__ __align__(16) u16 Ks[2][KBLK * 256];   // [tok][k], swizzled
  __shared__ __align__(16) u16 Vs[2][DHEAD * KBLK]; // [d][tok], swizzled
  __shared__ __align__(16) u16 Pl[8][16 * KBLK];    // per-wave P scratch

  const int tid = threadIdx.x;
  const int lane = tid & 63, w = tid >> 6;
  const int bh = blockIdx.y, b = bh >> 2, h = bh & 3;
  const int t0 = blockIdx.x * QBLK;

  const u16* qkv_b = qkv + (size_t)b * NTOK * H3;
  const u16* vt_bh = vT + (size_t)bh * (size_t)DHEAD * NTOK;
  const int kcol = DIMD + h * DHEAD;   // K columns in qkv

  // Q fragments: row = t0 + w*16 + (lane&15); k = ks*32 + (lane>>4)*8
  bf16v8 qf[8];
  {
    const size_t qoff = (size_t)(t0 + w * 16 + (lane & 15)) * H3 + h * DHEAD +
                        (lane >> 4) * 8;
#pragma unroll
    for (int ks = 0; ks < 8; ks++)
      qf[ks] = *reinterpret_cast<const bf16v8*>(qkv_b + qoff + ks * 32);
  }

  f32v4 o[16];
#pragma unroll
  for (int d = 0; d < 16; d++) o[d] = (f32v4){0.f, 0.f, 0.f, 0.f};
  float m[4] = {-1e30f, -1e30f, -1e30f, -1e30f};
  float lsum[4] = {0.f, 0.f, 0.f, 0.f};

  auto stage = [&](int kt) {
    const int buf = kt & 1;
    const int kt0 = kt * KBLK;
    // K tile: 64 rows x 512B; 2048 16B-chunks; linear LDS dest, swz source
#pragma unroll
    for (int i = 0; i < 4; i++) {
      const int c = i * 512 + tid;
      const int row = c >> 5;
      const int cb = ((c & 31) * 16) ^ ((row & 7) << 4);
      gload16(qkv_b + (size_t)(kt0 + row) * H3 + kcol + (cb >> 1),
              (char*)&Ks[buf][0] + (size_t)c * 16);
    }
    // V tile: 256 rows x 128B
#pragma unroll
    for (int i = 0; i < 4; i++) {
      const int c = i * 512 + tid;
      const int row = c >> 3;
      const int cb = ((c & 7) * 16) ^ ((row & 7) << 4);
      gload16(vt_bh + (size_t)row * NTOK + kt0 + (cb >> 1),
              (char*)&Vs[buf][0] + (size_t)c * 16);
    }
  };

  stage(0);

  for (int kt = 0; kt < NKT; kt++) {
    __syncthreads();            // drains stage(kt); all waves done with kt-1
    if (kt + 1 < NKT) stage(kt + 1);

    const char* kb = (const char*)&Ks[kt & 1][0];
    const char* vb = (const char*)&Vs[kt & 1][0];

    // ---- S = Q K^T (wave: 16 rows x 64 tok) ----
    f32v4 s[4];
#pragma unroll
    for (int nf = 0; nf < 4; nf++) s[nf] = (f32v4){0.f, 0.f, 0.f, 0.f};
#pragma unroll
    for (int ks = 0; ks < 8; ks++) {
#pragma unroll
      for (int nf = 0; nf < 4; nf++) {
        const int tok = nf * 16 + (lane & 15);
        const int cb = (ks * 64 + (lane >> 4) * 16) ^ ((tok & 7) << 4);
        const bf16v8 kf = *reinterpret_cast<const bf16v8*>(kb + tok * 512 + cb);
        s[nf] = __builtin_amdgcn_mfma_f32_16x16x32_bf16(qf[ks], kf, s[nf], 0, 0, 0);
      }
    }

    // ---- online softmax (rows = (lane>>4)*4+j; 16 lanes share a row) ----
    float pmax[4], corr[4];
#pragma unroll
    for (int j = 0; j < 4; j++) {
      float a = fmaxf(fmaxf(s[0][j], s[1][j]), fmaxf(s[2][j], s[3][j]));
#pragma unroll
      for (int off = 1; off < 16; off <<= 1)
        a = fmaxf(a, __shfl_xor(a, off, 64));
      pmax[j] = a * 0.03125f;
      const float mn = fmaxf(m[j], pmax[j]);
      corr[j] = __expf(m[j] - mn);
      m[j] = mn;
      lsum[j] *= corr[j];
    }
#pragma unroll
    for (int d = 0; d < 16; d++)
#pragma unroll
      for (int j = 0; j < 4; j++) o[d][j] *= corr[j];

    float p[4][4], rsum[4] = {0.f, 0.f, 0.f, 0.f};
#pragma unroll
    for (int nf = 0; nf < 4; nf++)
#pragma unroll
      for (int j = 0; j < 4; j++) {
        p[nf][j] = __expf(s[nf][j] * 0.03125f - m[j]);
        rsum[j] += p[nf][j];
      }
#pragma unroll
    for (int j = 0; j < 4; j++) {
#pragma unroll
      for (int off = 1; off < 16; off <<= 1)
        rsum[j] += __shfl_xor(rsum[j], off, 64);
      lsum[j] += rsum[j];
    }

    // ---- P -> per-wave LDS scratch (swizzled), re-read as A-frags ----
    char* pw = (char*)&Pl[w][0];
#pragma unroll
    for (int nf = 0; nf < 4; nf++)
#pragma unroll
      for (int j = 0; j < 4; j++) {
        const int r = (lane >> 4) * 4 + j;
        const int cbyte = ((nf * 16 + (lane & 15)) * 2) ^ ((r & 7) << 4);
        *(u16*)(pw + r * 128 + cbyte) = f2bf(p[nf][j]);
      }
    bf16v8 pa[2];
#pragma unroll
    for (int c = 0; c < 2; c++) {
      const int r = lane & 15;
      const int cb = (c * 64 + (lane >> 4) * 16) ^ ((r & 7) << 4);
      pa[c] = *reinterpret_cast<const bf16v8*>(pw + r * 128 + cb);
    }

    // ---- O += P V ----
#pragma unroll
    for (int c = 0; c < 2; c++)
#pragma unroll
      for (int df = 0; df < 16; df++) {
        const int d = df * 16 + (lane & 15);
        const int cb = (c * 64 + (lane >> 4) * 16) ^ ((d & 7) << 4);
        const bf16v8 vf = *reinterpret_cast<const bf16v8*>(vb + d * 128 + cb);
        o[df] = __builtin_amdgcn_mfma_f32_16x16x32_bf16(pa[c], vf, o[df], 0, 0, 0);
      }
  }

  // ---- epilogue: O/l -> obuf[b*NTOK + row][h*256 + d] ----
  float rl[4];
#pragma unroll
  for (int j = 0; j < 4; j++) rl[j] = 1.f / lsum[j];
  const size_t rbase = (size_t)b * NTOK + t0 + w * 16 + (lane >> 4) * 4;
  const int cbase = h * DHEAD + (lane & 15);
#pragma unroll
  for (int df = 0; df < 16; df++)
#pragma unroll
    for (int j = 0; j < 4; j++)
      obuf[(rbase + j) * DIMD + cbase + df * 16] = f2bf(o[df][j] * rl[j]);
}

// ---------------- GEMM: C[M,N] = A[M,K] * Bt[N,K]^T  (all bf16, fp32 acc) ---
// EPI: 0 store bf16; 2 fp32 resid += acc+bias; 3 bf16 gelu(acc+bias);
//      4 fp32 acc+bias+pos (conv epilogue).
template <int EPI>
__global__ __launch_bounds__(256) void gemm_bt(
    const u16* __restrict__ A, int lda,
    const u16* __restrict__ Bt, int ldb,
    int K, void* __restrict__ Cp, int ldc,
    const float* __restrict__ bias, const float* __restrict__ extra,
    float scale) {
  __shared__ __align__(16) u16 As[128 * 32];
  __shared__ __align__(16) u16 Bs[128 * 32];
  const int tid = threadIdx.x;
  const int bm = blockIdx.x, bn = blockIdx.y;

  const int c0 = tid, c1 = tid + 256;
  const u16* Ab = A + (size_t)(bm * 128) * lda;
  const u16* Bb = Bt + (size_t)(bn * 128) * ldb;
  const size_t a0 = (size_t)(c0 >> 2) * lda + (c0 & 3) * 8;
  const size_t a1 = (size_t)(c1 >> 2) * lda + (c1 & 3) * 8;
  const size_t b0 = (size_t)(c0 >> 2) * ldb + (c0 & 3) * 8;
  const size_t b1 = (size_t)(c1 >> 2) * ldb + (c1 & 3) * 8;

  const int lane = tid & 63;
  const int wv = tid >> 6;
  const int wm = (wv >> 1) * 64;
  const int wn = (wv & 1) * 64;
  const int fr = lane & 15;
  const int fk = (lane >> 4) * 8;

  f32v4 acc[4][4];
#pragma unroll
  for (int m = 0; m < 4; m++)
#pragma unroll
    for (int n = 0; n < 4; n++) acc[m][n] = (f32v4){0.f, 0.f, 0.f, 0.f};

  for (int k0 = 0; k0 < K; k0 += 32) {
    __syncthreads();
    gload16(Ab + a0 + k0, As + (size_t)c0 * 8);
    gload16(Ab + a1 + k0, As + (size_t)c1 * 8);
    gload16(Bb + b0 + k0, Bs + (size_t)c0 * 8);
    gload16(Bb + b1 + k0, Bs + (size_t)c1 * 8);
    __syncthreads();

    bf16v8 af[4], bq[4];
#pragma unroll
    for (int m = 0; m < 4; m++)
      af[m] = *reinterpret_cast<const bf16v8*>(&As[(wm + m * 16 + fr) * 32 + fk]);
#pragma unroll
    for (int n = 0; n < 4; n++)
      bq[n] = *reinterpret_cast<const bf16v8*>(&Bs[(wn + n * 16 + fr) * 32 + fk]);
#pragma unroll
    for (int m = 0; m < 4; m++)
#pragma unroll
      for (int n = 0; n < 4; n++)
        acc[m][n] =
            __builtin_amdgcn_mfma_f32_16x16x32_bf16(af[m], bq[n], acc[m][n], 0, 0, 0);
  }

  const int rbase = bm * 128 + wm + (lane >> 4) * 4;
  const int cbase = bn * 128 + wn + fr;
#pragma unroll
  for (int m = 0; m < 4; m++) {
#pragma unroll
    for (int n = 0; n < 4; n++) {
      const int col = cbase + n * 16;
#pragma unroll
      for (int j = 0; j < 4; j++) {
        const int rowi = rbase + m * 16 + j;
        const float v = acc[m][n][j];
        if (EPI == 0) {
          ((u16*)Cp)[(size_t)rowi * ldc + col] = f2bf(v);
        } else if (EPI == 2) {
          float* p = (float*)Cp + (size_t)rowi * ldc + col;
          *p += v + bias[col];
        } else if (EPI == 3) {
          float t = v + bias[col];
          t = 0.5f * t * (1.f + erff(t * 0.70710678118654752f));
          ((u16*)Cp)[(size_t)rowi * ldc + col] = f2bf(t);
        } else {
          ((float*)Cp)[(size_t)rowi * ldc + col] =
              v + bias[col] + extra[(size_t)(rowi % NTOK) * DIMD + col];
        }
      }
    }
  }
}

// ---------------------------------------------------------------------------
// workspace layout (bytes) — peak ~158 MB
// ---------------------------------------------------------------------------
#define SZ_QKVT ((size_t)H3 * DIMD * 2)
#define SZ_OUTT ((size_t)DIMD * DIMD * 2)
#define SZ_FC1T ((size_t)MLPH * DIMD * 2)
#define SZ_FC2T ((size_t)DIMD * MLPH * 2)
#define SZ_CONVW ((size_t)DIMD * 256 * 2)
#define SZ_X ((size_t)TTOT * DIMD * 4)
#define SZ_XO ((size_t)TTOT * DIMD * 2)            // x1 | obuf
#define SZ_BIGA ((size_t)TTOT * H3 * 2 + (size_t)8 * DHEAD * NTOK * 2) // qkv+vT | hbuf | patchA

#define OFF_QKVT ((size_t)0)
#define OFF_OUTT (OFF_QKVT + SZ_QKVT)
#define OFF_FC1T (OFF_OUTT + SZ_OUTT)
#define OFF_FC2T (OFF_FC1T + SZ_FC1T)
#define OFF_CONVW (OFF_FC2T + SZ_FC2T)
#define OFF_X (OFF_CONVW + SZ_CONVW)
#define OFF_XO (OFF_X + SZ_X)
#define OFF_BIGA (OFF_XO + SZ_XO)
#define WS_NEED (OFF_BIGA + SZ_BIGA)

extern "C" void kernel_launch(void* const* d_in, const int* in_sizes, int n_in,
                              void* d_out, int out_size, void* d_ws, size_t ws_size,
                              hipStream_t stream) {
  const float* img = (const float*)d_in[0];
  const float* conv_w = (const float*)d_in[1];
  const float* conv_b = (const float*)d_in[2];
  const float* pos = (const float*)d_in[3];
  const float* ln1_g = (const float*)d_in[4];
  const float* ln1_b = (const float*)d_in[5];
  const float* qkv_w = (const float*)d_in[6];
  const float* out_w = (const float*)d_in[7];
  const float* out_b = (const float*)d_in[8];
  const float* ln2_g = (const float*)d_in[9];
  const float* ln2_b = (const float*)d_in[10];
  const float* fc1_w = (const float*)d_in[11];
  const float* fc1_b = (const float*)d_in[12];
  const float* fc2_w = (const float*)d_in[13];
  const float* fc2_b = (const float*)d_in[14];
  const float* lnf_g = (const float*)d_in[15];
  const float* lnf_b = (const float*)d_in[16];
  float* out = (float*)d_out;

  if (ws_size < WS_NEED) return;

  char* ws = (char*)d_ws;
  u16* qkvT = (u16*)(ws + OFF_QKVT);
  u16* outT = (u16*)(ws + OFF_OUTT);
  u16* fc1T = (u16*)(ws + OFF_FC1T);
  u16* fc2T = (u16*)(ws + OFF_FC2T);
  u16* convW = (u16*)(ws + OFF_CONVW);
  float* x = (float*)(ws + OFF_X);
  u16* x1 = (u16*)(ws + OFF_XO);
  u16* obuf = (u16*)(ws + OFF_XO);     // aliased with x1 (disjoint lifetime)
  u16* qkv = (u16*)(ws + OFF_BIGA);
  u16* vT = (u16*)(ws + OFF_BIGA + (size_t)TTOT * H3 * 2);
  u16* hbuf = (u16*)(ws + OFF_BIGA);   // aliased (MLP phase)
  u16* patchA = (u16*)(ws + OFF_BIGA); // aliased (pre-layer phase)

  const dim3 tb(32, 8);

  // ---- patch embed ----
  convert_bf16<<<1024, 256, 0, stream>>>(conv_w, convW, DIMD * 256);
  patch_extract<<<TTOT, 256, 0, stream>>>(img, patchA);
  gemm_bt<4><<<dim3(TTOT / 128, DIMD / 128, 1), 256, 0, stream>>>(
      patchA, 256, convW, 256, 256, x, DIMD, conv_b, pos, 1.f);

  for (int l = 0; l < NLAYER; l++) {
    transpose_w<<<dim3(H3 / 32, DIMD / 32, 1), tb, 0, stream>>>(
        qkv_w + (size_t)l * DIMD * H3, qkvT, DIMD, H3);
    transpose_w<<<dim3(DIMD / 32, DIMD / 32, 1), tb, 0, stream>>>(
        out_w + (size_t)l * DIMD * DIMD, outT, DIMD, DIMD);
    transpose_w<<<dim3(MLPH / 32, DIMD / 32, 1), tb, 0, stream>>>(
        fc1_w + (size_t)l * DIMD * MLPH, fc1T, DIMD, MLPH);
    transpose_w<<<dim3(DIMD / 32, MLPH / 32, 1), tb, 0, stream>>>(
        fc2_w + (size_t)l * MLPH * DIMD, fc2T, MLPH, DIMD);

    // LN1 -> x1 (bf16)
    ln_kernel<0><<<TTOT, 256, 0, stream>>>(x, ln1_g + l * DIMD, ln1_b + l * DIMD, x1);
    // QKV
    gemm_bt<0><<<dim3(TTOT / 128, H3 / 128, 1), 256, 0, stream>>>(
        x1, DIMD, qkvT, DIMD, DIMD, qkv, H3, nullptr, nullptr, 1.f);
    // V -> vT
    transpose_v<<<dim3(NTOK / 32, DHEAD / 32, 8), tb, 0, stream>>>(qkv, vT);

    // fused attention -> obuf
    flash_attn<<<dim3(NTOK / QBLK, 8, 1), 512, 0, stream>>>(qkv, vT, obuf);

    // x += o @ out_w + out_b
    gemm_bt<2><<<dim3(TTOT / 128, DIMD / 128, 1), 256, 0, stream>>>(
        obuf, DIMD, outT, DIMD, DIMD, x, DIMD, out_b + l * DIMD, nullptr, 1.f);
    // LN2 -> x1
    ln_kernel<0><<<TTOT, 256, 0, stream>>>(x, ln2_g + l * DIMD, ln2_b + l * DIMD, x1);
    // h = gelu(x1 @ fc1 + b)
    gemm_bt<3><<<dim3(TTOT / 128, MLPH / 128, 1), 256, 0, stream>>>(
        x1, DIMD, fc1T, DIMD, DIMD, hbuf, MLPH, fc1_b + l * MLPH, nullptr, 1.f);
    // x += h @ fc2 + b
    gemm_bt<2><<<dim3(TTOT / 128, DIMD / 128, 1), 256, 0, stream>>>(
        hbuf, MLPH, fc2T, MLPH, MLPH, x, DIMD, fc2_b + l * DIMD, nullptr, 1.f);
  }

  ln_kernel<1><<<TTOT, 256, 0, stream>>>(x, lnf_g, lnf_b, out);
}